// Round 1
// baseline (335.809 us; speedup 1.0000x reference)
//
#include <hip/hip_runtime.h>

typedef unsigned short u16;
typedef short bf16x8 __attribute__((ext_vector_type(8)));
typedef float f32x4 __attribute__((ext_vector_type(4)));

__device__ __forceinline__ u16 f2bf(float f) {
  union { float f; unsigned u; } c; c.f = f;
  unsigned r = (c.u + 0x7FFFu + ((c.u >> 16) & 1u)) >> 16;
  return (u16)r;
}
__device__ __forceinline__ float bf2f(u16 h) {
  union { unsigned u; float f; } c; c.u = ((unsigned)h) << 16;
  return c.f;
}
__device__ __forceinline__ void gload16(const void* g, void* l) {
  __builtin_amdgcn_global_load_lds(
      (const __attribute__((address_space(1))) unsigned*)g,
      (__attribute__((address_space(3))) unsigned*)l, 16, 0, 0);
}

// ---------------------------------------------------------------------------
// Weight prep: w_qkv [512,1536] -> wqkvT bf16 [1536,512]; w_out [512,512] -> woutT bf16 [512,512]
// ---------------------------------------------------------------------------
__global__ __launch_bounds__(256) void prep_weights(
    const float* __restrict__ w_qkv, const float* __restrict__ w_out,
    u16* __restrict__ wqkvT, u16* __restrict__ woutT) {
  int i = blockIdx.x * 256 + threadIdx.x;
  const int T1 = 1536 * 512;
  if (i < T1) {
    int n = i >> 9, c = i & 511;
    wqkvT[i] = f2bf(w_qkv[(size_t)c * 1536 + n]);
  } else {
    int j = i - T1;
    int n = j >> 9, c = j & 511;
    woutT[j] = f2bf(w_out[(size_t)c * 512 + n]);
  }
}

// ---------------------------------------------------------------------------
// GroupNorm: x fp32 [32,1024,512] -> z bf16, 32 groups of 16 ch, stats over (hw, 16ch)
// one block per (b,g): 16384 elements
// ---------------------------------------------------------------------------
__global__ __launch_bounds__(256) void groupnorm_k(
    const float* __restrict__ x, const float* __restrict__ scale,
    const float* __restrict__ bias, u16* __restrict__ z) {
  const int blk = blockIdx.x, b = blk >> 5, g = blk & 31;
  const float* xb = x + (size_t)b * 524288 + g * 16;
  u16* zb = z + (size_t)b * 524288 + g * 16;
  const int tid = threadIdx.x, lane = tid & 63, wid = tid >> 6;

  float4 vv[16];
  float s = 0.f, ss = 0.f;
#pragma unroll
  for (int i = 0; i < 16; ++i) {
    int e = (i * 256 + tid) * 4;
    int hw = e >> 4, j = e & 15;
    vv[i] = *(const float4*)&xb[(size_t)hw * 512 + j];
    s += vv[i].x + vv[i].y + vv[i].z + vv[i].w;
    ss += vv[i].x * vv[i].x + vv[i].y * vv[i].y + vv[i].z * vv[i].z + vv[i].w * vv[i].w;
  }
#pragma unroll
  for (int off = 32; off; off >>= 1) {
    s += __shfl_xor(s, off);
    ss += __shfl_xor(ss, off);
  }
  __shared__ float rs[4], rq[4];
  if (!lane) { rs[wid] = s; rq[wid] = ss; }
  __syncthreads();
  float S_ = rs[0] + rs[1] + rs[2] + rs[3];
  float Q_ = rq[0] + rq[1] + rq[2] + rq[3];
  const float inv_n = 1.f / 16384.f;
  float mean = S_ * inv_n;
  float var = Q_ * inv_n - mean * mean;
  float rstd = rsqrtf(var + 1e-5f);

  int j0 = (tid * 4) & 15;
  float sc0 = scale[g * 16 + j0 + 0] * rstd, sc1 = scale[g * 16 + j0 + 1] * rstd;
  float sc2 = scale[g * 16 + j0 + 2] * rstd, sc3 = scale[g * 16 + j0 + 3] * rstd;
  float bi0 = bias[g * 16 + j0 + 0] - mean * sc0, bi1 = bias[g * 16 + j0 + 1] - mean * sc1;
  float bi2 = bias[g * 16 + j0 + 2] - mean * sc2, bi3 = bias[g * 16 + j0 + 3] - mean * sc3;
#pragma unroll
  for (int i = 0; i < 16; ++i) {
    int e = (i * 256 + tid) * 4;
    int hw = e >> 4, j = e & 15;
    ushort4 o;
    o.x = f2bf(vv[i].x * sc0 + bi0);
    o.y = f2bf(vv[i].y * sc1 + bi1);
    o.z = f2bf(vv[i].z * sc2 + bi2);
    o.w = f2bf(vv[i].w * sc3 + bi3);
    *(ushort4*)&zb[(size_t)hw * 512 + j] = o;
  }
}

// ---------------------------------------------------------------------------
// GEMM: C[M,N] = A[M,K] @ Bt[N,K]^T    (both operands row-major over K)
// 128x128 tile, BK=64, 4 waves (2x2), each wave 64x64 (4x4 frags of 16x16)
// EPI 0: qkv split (+bias, q scaled)   EPI 1: bf16 store   EPI 2: fp32 +bias+resid
// ---------------------------------------------------------------------------
#define QSCALE 0.04419417382415922f

template <int EPI>
__global__ __launch_bounds__(256, 2) void gemm_bt(
    const u16* __restrict__ A, const u16* __restrict__ Bt,
    int M, int N, int K,
    long long sAb, long long sBb, long long sCb,
    const float* __restrict__ bias, const float* __restrict__ resid,
    u16* __restrict__ qb, u16* __restrict__ kb, u16* __restrict__ vb,
    u16* __restrict__ outb, float* __restrict__ outf) {
  const int bz = blockIdx.z;
  A += (size_t)bz * sAb;
  Bt += (size_t)bz * sBb;

  __shared__ u16 As[128 * 64];
  __shared__ u16 Bs[128 * 64];

  const int tid = threadIdx.x;
  const int lane = tid & 63, wid = tid >> 6;
  const int wm = wid >> 1, wn = wid & 1;
  const int l15 = lane & 15, l4 = lane >> 4;

  const int m0 = blockIdx.y * 128;
  const int n0 = blockIdx.x * 128;

  f32x4 acc[4][4];
#pragma unroll
  for (int mi = 0; mi < 4; ++mi)
#pragma unroll
    for (int ni = 0; ni < 4; ++ni)
#pragma unroll
      for (int r = 0; r < 4; ++r) acc[mi][ni][r] = 0.f;

  for (int k0 = 0; k0 < K; k0 += 64) {
#pragma unroll
    for (int it = 0; it < 4; ++it) {
      int c = it * 256 + tid;
      int row = c >> 3, kc = c & 7;
      int ldsoff = (it * 256 + wid * 64) * 8;  // ushorts, wave-uniform
      gload16(A + (size_t)(m0 + row) * K + (k0 + kc * 8), &As[ldsoff]);
    }
#pragma unroll
    for (int it = 0; it < 4; ++it) {
      int c = it * 256 + tid;
      int row = c >> 3, kc = c & 7;
      int ldsoff = (it * 256 + wid * 64) * 8;
      gload16(Bt + (size_t)(n0 + row) * K + (k0 + kc * 8), &Bs[ldsoff]);
    }
    asm volatile("s_waitcnt vmcnt(0)" ::: "memory");
    __syncthreads();

#pragma unroll
    for (int kk = 0; kk < 64; kk += 32) {
      bf16x8 af[4], bfr[4];
#pragma unroll
      for (int mi = 0; mi < 4; ++mi)
        af[mi] = *(const bf16x8*)&As[(wm * 64 + mi * 16 + l15) * 64 + kk + l4 * 8];
#pragma unroll
      for (int ni = 0; ni < 4; ++ni)
        bfr[ni] = *(const bf16x8*)&Bs[(wn * 64 + ni * 16 + l15) * 64 + kk + l4 * 8];
#pragma unroll
      for (int mi = 0; mi < 4; ++mi)
#pragma unroll
        for (int ni = 0; ni < 4; ++ni)
          acc[mi][ni] = __builtin_amdgcn_mfma_f32_16x16x32_bf16(af[mi], bfr[ni], acc[mi][ni], 0, 0, 0);
    }
    __syncthreads();
  }

#pragma unroll
  for (int mi = 0; mi < 4; ++mi) {
#pragma unroll
    for (int ni = 0; ni < 4; ++ni) {
      int gr0 = m0 + wm * 64 + mi * 16 + l4 * 4;
      int gc = n0 + wn * 64 + ni * 16 + l15;
#pragma unroll
      for (int r = 0; r < 4; ++r) {
        float val = acc[mi][ni][r];
        int gr = gr0 + r;
        if (EPI == 0) {
          int bsel = gc >> 9, cin = gc & 511;
          float vvv = val + bias[gc];
          if (bsel == 0) vvv *= QSCALE;
          u16* dst = (bsel == 0) ? qb : (bsel == 1) ? kb : vb;
          dst[(size_t)gr * 512 + cin] = f2bf(vvv);
        } else if (EPI == 1) {
          outb[(size_t)bz * sCb + (size_t)gr * N + gc] = f2bf(val);
        } else {
          outf[(size_t)gr * N + gc] = val + bias[gc] + resid[(size_t)gr * N + gc];
        }
      }
    }
  }
}

// ---------------------------------------------------------------------------
// Row softmax over S bf16 [32768 rows][1024], in place, fp32 math
// ---------------------------------------------------------------------------
__global__ __launch_bounds__(256) void softmax_rows(u16* __restrict__ S) {
  const size_t row = blockIdx.x;
  u16* p = S + row * 1024;
  const int tid = threadIdx.x, lane = tid & 63, wid = tid >> 6;
  ushort4 raw = ((const ushort4*)p)[tid];
  float v0 = bf2f(raw.x), v1 = bf2f(raw.y), v2 = bf2f(raw.z), v3 = bf2f(raw.w);
  float mx = fmaxf(fmaxf(v0, v1), fmaxf(v2, v3));
#pragma unroll
  for (int off = 32; off; off >>= 1) mx = fmaxf(mx, __shfl_xor(mx, off));
  __shared__ float red[8];
  if (!lane) red[wid] = mx;
  __syncthreads();
  mx = fmaxf(fmaxf(red[0], red[1]), fmaxf(red[2], red[3]));
  float e0 = __expf(v0 - mx), e1 = __expf(v1 - mx), e2 = __expf(v2 - mx), e3 = __expf(v3 - mx);
  float s = e0 + e1 + e2 + e3;
#pragma unroll
  for (int off = 32; off; off >>= 1) s += __shfl_xor(s, off);
  if (!lane) red[4 + wid] = s;
  __syncthreads();
  float inv = 1.0f / (red[4] + red[5] + red[6] + red[7]);
  ushort4 o;
  o.x = f2bf(e0 * inv); o.y = f2bf(e1 * inv); o.z = f2bf(e2 * inv); o.w = f2bf(e3 * inv);
  ((ushort4*)p)[tid] = o;
}

// ---------------------------------------------------------------------------
// V transpose: v [32][1024][512] -> vt [32][512][1024], bf16, 32x32 tiles
// ---------------------------------------------------------------------------
__global__ __launch_bounds__(256) void transpose_v(const u16* __restrict__ v, u16* __restrict__ vt) {
  __shared__ u16 t[32][33];
  const int b = blockIdx.z;
  const int c0 = blockIdx.x * 32;
  const int p0 = blockIdx.y * 32;
  const int tx = threadIdx.x & 31, ty = threadIdx.x >> 5;
  const u16* vbp = v + (size_t)b * 1024 * 512;
  u16* vtb = vt + (size_t)b * 512 * 1024;
#pragma unroll
  for (int j = 0; j < 32; j += 8)
    t[ty + j][tx] = vbp[(size_t)(p0 + ty + j) * 512 + c0 + tx];
  __syncthreads();
#pragma unroll
  for (int j = 0; j < 32; j += 8)
    vtb[(size_t)(c0 + ty + j) * 1024 + p0 + tx] = t[tx][ty + j];
}

// ---------------------------------------------------------------------------
extern "C" void kernel_launch(void* const* d_in, const int* in_sizes, int n_in,
                              void* d_out, int out_size, void* d_ws, size_t ws_size,
                              hipStream_t stream) {
  const float* x = (const float*)d_in[0];
  // d_in[1] = t (unused by reference)
  const float* gn_scale = (const float*)d_in[2];
  const float* gn_bias = (const float*)d_in[3];
  const float* w_qkv = (const float*)d_in[4];
  const float* b_qkv = (const float*)d_in[5];
  const float* w_out = (const float*)d_in[6];
  const float* b_out = (const float*)d_in[7];
  float* out = (float*)d_out;

  char* ws = (char*)d_ws;
  const size_t MB = 1024ull * 1024ull;
  u16* qb = (u16*)(ws + 0 * MB);      // 32 MB  [32768][512]
  u16* kb = (u16*)(ws + 32 * MB);     // 32 MB
  u16* vb = (u16*)(ws + 64 * MB);     // 32 MB
  u16* vt = (u16*)(ws + 96 * MB);     // 32 MB  [32][512][1024]
  u16* zO = (u16*)(ws + 128 * MB);    // 32 MB  z, later reused as O
  u16* S = (u16*)(ws + 160 * MB);     // 64 MB  [32][1024][1024]
  u16* wqkvT = (u16*)(ws + 224 * MB); // 1.5 MB [1536][512]
  u16* woutT = (u16*)(ws + 226 * MB); // 0.5 MB [512][512]

  prep_weights<<<4096, 256, 0, stream>>>(w_qkv, w_out, wqkvT, woutT);
  groupnorm_k<<<1024, 256, 0, stream>>>(x, gn_scale, gn_bias, zO);

  // QKV: z[32768,512] @ wqkvT^T -> q,k,v (q pre-scaled by 1/sqrt(512))
  gemm_bt<0><<<dim3(12, 256, 1), 256, 0, stream>>>(
      zO, wqkvT, 32768, 1536, 512, 0, 0, 0, b_qkv, nullptr, qb, kb, vb, nullptr, nullptr);

  transpose_v<<<dim3(16, 32, 32), 256, 0, stream>>>(vb, vt);

  // S = q @ k^T (batched over 32)
  gemm_bt<1><<<dim3(8, 8, 32), 256, 0, stream>>>(
      qb, kb, 1024, 1024, 512, 1024 * 512, 1024 * 512, 1024 * 1024,
      nullptr, nullptr, nullptr, nullptr, nullptr, S, nullptr);

  softmax_rows<<<32768, 256, 0, stream>>>(S);

  // O = P @ V  (vt is [512][1024] per batch)
  gemm_bt<1><<<dim3(4, 8, 32), 256, 0, stream>>>(
      S, vt, 1024, 512, 1024, 1024 * 1024, 512 * 1024, 1024 * 512,
      nullptr, nullptr, nullptr, nullptr, nullptr, zO, nullptr);

  // out = O @ w_out^T + b_out + x
  gemm_bt<2><<<dim3(4, 256, 1), 256, 0, stream>>>(
      zO, woutT, 32768, 512, 512, 0, 0, 0, b_out, x,
      nullptr, nullptr, nullptr, nullptr, out);
}

// Round 2
// 306.289 us; speedup vs baseline: 1.0964x; 1.0964x over previous
//
#include <hip/hip_runtime.h>

typedef unsigned short u16;
typedef short bf16x8 __attribute__((ext_vector_type(8)));
typedef float f32x4 __attribute__((ext_vector_type(4)));

__device__ __forceinline__ u16 f2bf(float f) {
  union { float f; unsigned u; } c; c.f = f;
  unsigned r = (c.u + 0x7FFFu + ((c.u >> 16) & 1u)) >> 16;
  return (u16)r;
}
__device__ __forceinline__ float bf2f(u16 h) {
  union { unsigned u; float f; } c; c.u = ((unsigned)h) << 16;
  return c.f;
}
__device__ __forceinline__ void gload16(const void* g, void* l) {
  __builtin_amdgcn_global_load_lds(
      (const __attribute__((address_space(1))) unsigned*)g,
      (__attribute__((address_space(3))) unsigned*)l, 16, 0, 0);
}

// ---------------------------------------------------------------------------
// Weight prep: w_qkv [512,1536] -> wqkvT bf16 [1536,512]; w_out -> woutT [512,512]
// ---------------------------------------------------------------------------
__global__ __launch_bounds__(256) void prep_weights(
    const float* __restrict__ w_qkv, const float* __restrict__ w_out,
    u16* __restrict__ wqkvT, u16* __restrict__ woutT) {
  int i = blockIdx.x * 256 + threadIdx.x;
  const int T1 = 1536 * 512;
  if (i < T1) {
    int n = i >> 9, c = i & 511;
    wqkvT[i] = f2bf(w_qkv[(size_t)c * 1536 + n]);
  } else {
    int j = i - T1;
    int n = j >> 9, c = j & 511;
    woutT[j] = f2bf(w_out[(size_t)c * 512 + n]);
  }
}

// ---------------------------------------------------------------------------
// GroupNorm: x fp32 [32,1024,512] -> z bf16; 32 groups of 16 ch
// ---------------------------------------------------------------------------
__global__ __launch_bounds__(256) void groupnorm_k(
    const float* __restrict__ x, const float* __restrict__ scale,
    const float* __restrict__ bias, u16* __restrict__ z) {
  const int blk = blockIdx.x, b = blk >> 5, g = blk & 31;
  const float* xb = x + (size_t)b * 524288 + g * 16;
  u16* zb = z + (size_t)b * 524288 + g * 16;
  const int tid = threadIdx.x, lane = tid & 63, wid = tid >> 6;

  float4 vv[16];
  float s = 0.f, ss = 0.f;
#pragma unroll
  for (int i = 0; i < 16; ++i) {
    int e = (i * 256 + tid) * 4;
    int hw = e >> 4, j = e & 15;
    vv[i] = *(const float4*)&xb[(size_t)hw * 512 + j];
    s += vv[i].x + vv[i].y + vv[i].z + vv[i].w;
    ss += vv[i].x * vv[i].x + vv[i].y * vv[i].y + vv[i].z * vv[i].z + vv[i].w * vv[i].w;
  }
#pragma unroll
  for (int off = 32; off; off >>= 1) {
    s += __shfl_xor(s, off);
    ss += __shfl_xor(ss, off);
  }
  __shared__ float rs[4], rq[4];
  if (!lane) { rs[wid] = s; rq[wid] = ss; }
  __syncthreads();
  float S_ = rs[0] + rs[1] + rs[2] + rs[3];
  float Q_ = rq[0] + rq[1] + rq[2] + rq[3];
  const float inv_n = 1.f / 16384.f;
  float mean = S_ * inv_n;
  float var = Q_ * inv_n - mean * mean;
  float rstd = rsqrtf(var + 1e-5f);

  int j0 = (tid * 4) & 15;
  float sc0 = scale[g * 16 + j0 + 0] * rstd, sc1 = scale[g * 16 + j0 + 1] * rstd;
  float sc2 = scale[g * 16 + j0 + 2] * rstd, sc3 = scale[g * 16 + j0 + 3] * rstd;
  float bi0 = bias[g * 16 + j0 + 0] - mean * sc0, bi1 = bias[g * 16 + j0 + 1] - mean * sc1;
  float bi2 = bias[g * 16 + j0 + 2] - mean * sc2, bi3 = bias[g * 16 + j0 + 3] - mean * sc3;
#pragma unroll
  for (int i = 0; i < 16; ++i) {
    int e = (i * 256 + tid) * 4;
    int hw = e >> 4, j = e & 15;
    ushort4 o;
    o.x = f2bf(vv[i].x * sc0 + bi0);
    o.y = f2bf(vv[i].y * sc1 + bi1);
    o.z = f2bf(vv[i].z * sc2 + bi2);
    o.w = f2bf(vv[i].w * sc3 + bi3);
    *(ushort4*)&zb[(size_t)hw * 512 + j] = o;
  }
}

// ---------------------------------------------------------------------------
// 8-phase 256x256xBK64 GEMM: C[M,N] = A[M,K] @ Bt[N,K]^T
// 512 thr = 8 waves (2M x 4N), per-wave 128x64 C, acc[8][4].
// LDS: 2 dbuf x (A 256x64 + B 256x64) as 2 halves of [128][64], XOR-granule
// swizzle colg ^= row&7 (pre-swizzled global source, swizzled ds_read).
// Staging ownership: wave pair (wid>>1) owns one half-tile; issues its 8
// global_load_lds in phase 0; self-drains vmcnt(0) just before the K-tile
// boundary barrier (~3.5 phases of slack -> loads in flight across barriers).
// EPI 0: qkv split (+bias, q scaled)  EPI 1: bf16 store  EPI 2: fp32+bias+resid
// ---------------------------------------------------------------------------
#define QSCALE 0.04419417382415922f

template <int EPI>
__global__ __launch_bounds__(512, 2) void gemm8p(
    const u16* __restrict__ A, const u16* __restrict__ Bt,
    int gx, int gxy, int N, int K,
    long long sAb, long long sBb, long long sCb,
    const float* __restrict__ bias, const float* __restrict__ resid,
    u16* __restrict__ qb, u16* __restrict__ kb, u16* __restrict__ vb,
    u16* __restrict__ outb, float* __restrict__ outf) {
  // XCD-chunked bijective remap over the flattened grid (nb % 8 == 0 here)
  int nb = gridDim.x, orig = blockIdx.x, id = orig;
  if (!(nb & 7)) { int chunk = nb >> 3; id = (orig & 7) * chunk + (orig >> 3); }
  int z = id / gxy; int r2 = id - z * gxy;
  int by = r2 / gx; int bx = r2 - by * gx;

  const u16* Ab = A + (size_t)z * sAb;
  const u16* Bb = Bt + (size_t)z * sBb;

  __shared__ u16 As[2][2][8192];  // [buf][half][128*64]
  __shared__ u16 Bs[2][2][8192];

  const int tid = threadIdx.x;
  const int lane = tid & 63, wid = tid >> 6;
  const int wm = wid & 1, wn = wid >> 1;   // interleaves b-halves across SIMDs
  const int l15 = lane & 15, l4 = lane >> 4;
  const int m0 = by * 256, n0 = bx * 256;

  // staging ownership: wid 0,1 -> A h0; 2,3 -> A h1; 4,5 -> B h0; 6,7 -> B h1
  const int own_is_b = wid >> 2;
  const int own_h = (wid >> 1) & 1;
  const int prow = ((wid & 1) << 6) | lane;        // 0..127 within pair
  const int srow = prow >> 3;                      // row j*16 + srow
  const int scol = ((prow & 7) ^ (srow & 7)) << 3; // pre-swizzled src col (ushorts)
  const u16* own_base = (own_is_b ? Bb : Ab) +
      (size_t)((own_is_b ? n0 : m0) + own_h * 128 + srow) * K + scol;
  const int ldsbase = ((wid & 1) << 6) * 8;        // ushort offset of lane 0

  f32x4 acc[8][4];
#pragma unroll
  for (int i = 0; i < 8; ++i)
#pragma unroll
    for (int j = 0; j < 4; ++j)
#pragma unroll
      for (int r = 0; r < 4; ++r) acc[i][j][r] = 0.f;

  const int NT = K >> 6;

  auto stage = [&](int k0, int buf) {
    u16* l0 = (own_is_b ? &Bs[buf][own_h][0] : &As[buf][own_h][0]) + ldsbase;
    const u16* g0 = own_base + k0;
#pragma unroll
    for (int j = 0; j < 8; ++j)
      gload16(g0 + (size_t)(j * 16) * K, l0 + j * 1024);
  };

  // prologue: tile 0 into buf 0
  stage(0, 0);
  asm volatile("s_waitcnt vmcnt(0)" ::: "memory");
  __builtin_amdgcn_s_barrier();

  for (int t = 0; t < NT; ++t) {
    const int cur = t & 1;
    const bool pre = (t + 1 < NT);
    const u16* Ah = &As[cur][wm][0];
    const u16* Bh = &Bs[cur][wn >> 1][0];
    const int rbB = (wn & 1) << 6;
#pragma unroll
    for (int q = 0; q < 4; ++q) {
      const int mg = q >> 1, ng = q & 1;
      bf16x8 af[4][2], bq[2][2];
#pragma unroll
      for (int i = 0; i < 4; ++i) {
        const int rr = (mg * 4 + i) * 16 + l15;
        const int sw = rr & 7;
        af[i][0] = *(const bf16x8*)&Ah[rr * 64 + ((l4 ^ sw) << 3)];
        af[i][1] = *(const bf16x8*)&Ah[rr * 64 + (((4 + l4) ^ sw) << 3)];
      }
#pragma unroll
      for (int i = 0; i < 2; ++i) {
        const int rr = rbB + (ng * 2 + i) * 16 + l15;
        const int sw = rr & 7;
        bq[i][0] = *(const bf16x8*)&Bh[rr * 64 + ((l4 ^ sw) << 3)];
        bq[i][1] = *(const bf16x8*)&Bh[rr * 64 + (((4 + l4) ^ sw) << 3)];
      }
      if (q == 0 && pre) stage((t + 1) << 6, cur ^ 1);
      __builtin_amdgcn_s_barrier();
      asm volatile("s_waitcnt lgkmcnt(0)" ::: "memory");
      __builtin_amdgcn_s_setprio(1);
#pragma unroll
      for (int i = 0; i < 4; ++i)
#pragma unroll
        for (int jn = 0; jn < 2; ++jn) {
          acc[mg * 4 + i][ng * 2 + jn] = __builtin_amdgcn_mfma_f32_16x16x32_bf16(
              af[i][0], bq[jn][0], acc[mg * 4 + i][ng * 2 + jn], 0, 0, 0);
          acc[mg * 4 + i][ng * 2 + jn] = __builtin_amdgcn_mfma_f32_16x16x32_bf16(
              af[i][1], bq[jn][1], acc[mg * 4 + i][ng * 2 + jn], 0, 0, 0);
        }
      __builtin_amdgcn_s_setprio(0);
      if (q == 3 && pre) asm volatile("s_waitcnt vmcnt(0)" ::: "memory");
      __builtin_amdgcn_s_barrier();
    }
  }

  // epilogue
#pragma unroll
  for (int mi = 0; mi < 8; ++mi) {
#pragma unroll
    for (int ni = 0; ni < 4; ++ni) {
      int gr0 = m0 + wm * 128 + mi * 16 + l4 * 4;
      int gc = n0 + wn * 64 + ni * 16 + l15;
#pragma unroll
      for (int r = 0; r < 4; ++r) {
        float val = acc[mi][ni][r];
        int gr = gr0 + r;
        if (EPI == 0) {
          int bsel = gc >> 9, cin = gc & 511;
          float vvv = val + bias[gc];
          if (bsel == 0) vvv *= QSCALE;
          u16* dst = (bsel == 0) ? qb : (bsel == 1) ? kb : vb;
          dst[(size_t)gr * 512 + cin] = f2bf(vvv);
        } else if (EPI == 1) {
          outb[(size_t)z * sCb + (size_t)gr * N + gc] = f2bf(val);
        } else {
          outf[(size_t)gr * N + gc] = val + bias[gc] + resid[(size_t)gr * N + gc];
        }
      }
    }
  }
}

// ---------------------------------------------------------------------------
// Row softmax over S bf16 [32768 rows][1024], in place, fp32 math
// ---------------------------------------------------------------------------
__global__ __launch_bounds__(256) void softmax_rows(u16* __restrict__ S) {
  const size_t row = blockIdx.x;
  u16* p = S + row * 1024;
  const int tid = threadIdx.x, lane = tid & 63, wid = tid >> 6;
  ushort4 raw = ((const ushort4*)p)[tid];
  float v0 = bf2f(raw.x), v1 = bf2f(raw.y), v2 = bf2f(raw.z), v3 = bf2f(raw.w);
  float mx = fmaxf(fmaxf(v0, v1), fmaxf(v2, v3));
#pragma unroll
  for (int off = 32; off; off >>= 1) mx = fmaxf(mx, __shfl_xor(mx, off));
  __shared__ float red[8];
  if (!lane) red[wid] = mx;
  __syncthreads();
  mx = fmaxf(fmaxf(red[0], red[1]), fmaxf(red[2], red[3]));
  float e0 = __expf(v0 - mx), e1 = __expf(v1 - mx), e2 = __expf(v2 - mx), e3 = __expf(v3 - mx);
  float s = e0 + e1 + e2 + e3;
#pragma unroll
  for (int off = 32; off; off >>= 1) s += __shfl_xor(s, off);
  if (!lane) red[4 + wid] = s;
  __syncthreads();
  float inv = 1.0f / (red[4] + red[5] + red[6] + red[7]);
  ushort4 o;
  o.x = f2bf(e0 * inv); o.y = f2bf(e1 * inv); o.z = f2bf(e2 * inv); o.w = f2bf(e3 * inv);
  ((ushort4*)p)[tid] = o;
}

// ---------------------------------------------------------------------------
// V transpose: v [32][1024][512] -> vt [32][512][1024], bf16
// ---------------------------------------------------------------------------
__global__ __launch_bounds__(256) void transpose_v(const u16* __restrict__ v, u16* __restrict__ vt) {
  __shared__ u16 t[32][33];
  const int b = blockIdx.z;
  const int c0 = blockIdx.x * 32;
  const int p0 = blockIdx.y * 32;
  const int tx = threadIdx.x & 31, ty = threadIdx.x >> 5;
  const u16* vbp = v + (size_t)b * 1024 * 512;
  u16* vtb = vt + (size_t)b * 512 * 1024;
#pragma unroll
  for (int j = 0; j < 32; j += 8)
    t[ty + j][tx] = vbp[(size_t)(p0 + ty + j) * 512 + c0 + tx];
  __syncthreads();
#pragma unroll
  for (int j = 0; j < 32; j += 8)
    vtb[(size_t)(c0 + ty + j) * 1024 + p0 + tx] = t[tx][ty + j];
}

// ---------------------------------------------------------------------------
extern "C" void kernel_launch(void* const* d_in, const int* in_sizes, int n_in,
                              void* d_out, int out_size, void* d_ws, size_t ws_size,
                              hipStream_t stream) {
  const float* x = (const float*)d_in[0];
  const float* gn_scale = (const float*)d_in[2];
  const float* gn_bias = (const float*)d_in[3];
  const float* w_qkv = (const float*)d_in[4];
  const float* b_qkv = (const float*)d_in[5];
  const float* w_out = (const float*)d_in[6];
  const float* b_out = (const float*)d_in[7];
  float* out = (float*)d_out;

  char* ws = (char*)d_ws;
  const size_t MB = 1024ull * 1024ull;
  u16* qb = (u16*)(ws + 0 * MB);      // 32 MB  [32768][512]
  u16* kb = (u16*)(ws + 32 * MB);     // 32 MB
  u16* vb = (u16*)(ws + 64 * MB);     // 32 MB
  u16* vt = (u16*)(ws + 96 * MB);     // 32 MB  [32][512][1024]
  u16* zO = (u16*)(ws + 128 * MB);    // 32 MB  z, later reused as O
  u16* S = (u16*)(ws + 160 * MB);     // 64 MB  [32][1024][1024]
  u16* wqkvT = (u16*)(ws + 224 * MB); // 1.5 MB [1536][512]
  u16* woutT = (u16*)(ws + 226 * MB); // 0.5 MB [512][512]

  prep_weights<<<4096, 256, 0, stream>>>(w_qkv, w_out, wqkvT, woutT);
  groupnorm_k<<<1024, 256, 0, stream>>>(x, gn_scale, gn_bias, zO);

  // QKV: z[32768,512] @ wqkvT^T -> q,k,v  (grid 6x128 = 768)
  gemm8p<0><<<768, 512, 0, stream>>>(
      zO, wqkvT, 6, 768, 1536, 512, 0, 0, 0, b_qkv, nullptr,
      qb, kb, vb, nullptr, nullptr);

  transpose_v<<<dim3(16, 32, 32), 256, 0, stream>>>(vb, vt);

  // S = q @ k^T (batched over 32; grid 4x4x32 = 512)
  gemm8p<1><<<512, 512, 0, stream>>>(
      qb, kb, 4, 16, 1024, 512, 1024 * 512, 1024 * 512, 1024 * 1024,
      nullptr, nullptr, nullptr, nullptr, nullptr, S, nullptr);

  softmax_rows<<<32768, 256, 0, stream>>>(S);

  // O = P @ V  (vt is [512][1024] per batch; grid 2x4x32 = 256)
  gemm8p<1><<<256, 512, 0, stream>>>(
      S, vt, 2, 8, 512, 1024, 1024 * 1024, 512 * 1024, 1024 * 512,
      nullptr, nullptr, nullptr, nullptr, nullptr, zO, nullptr);

  // out = O @ w_out^T + b_out + x  (grid 2x128 = 256)
  gemm8p<2><<<256, 512, 0, stream>>>(
      zO, woutT, 2, 256, 512, 512, 0, 0, 0, b_out, x,
      nullptr, nullptr, nullptr, nullptr, out);
}

// Round 3
// 269.508 us; speedup vs baseline: 1.2460x; 1.1365x over previous
//
#include <hip/hip_runtime.h>

typedef unsigned short u16;
typedef short bf16x8 __attribute__((ext_vector_type(8)));
typedef float f32x4 __attribute__((ext_vector_type(4)));

__device__ __forceinline__ u16 f2bf(float f) {
  union { float f; unsigned u; } c; c.f = f;
  unsigned r = (c.u + 0x7FFFu + ((c.u >> 16) & 1u)) >> 16;
  return (u16)r;
}
__device__ __forceinline__ float bf2f(u16 h) {
  union { unsigned u; float f; } c; c.u = ((unsigned)h) << 16;
  return c.f;
}
__device__ __forceinline__ void gload16(const void* g, void* l) {
  __builtin_amdgcn_global_load_lds(
      (const __attribute__((address_space(1))) unsigned*)g,
      (__attribute__((address_space(3))) unsigned*)l, 16, 0, 0);
}

// ---------------------------------------------------------------------------
// Weight prep: w_qkv [512,1536] -> wqkvT bf16 [1536,512]; w_out -> woutT [512,512]
// ---------------------------------------------------------------------------
__global__ __launch_bounds__(256) void prep_weights(
    const float* __restrict__ w_qkv, const float* __restrict__ w_out,
    u16* __restrict__ wqkvT, u16* __restrict__ woutT) {
  int i = blockIdx.x * 256 + threadIdx.x;
  const int T1 = 1536 * 512;
  if (i < T1) {
    int n = i >> 9, c = i & 511;
    wqkvT[i] = f2bf(w_qkv[(size_t)c * 1536 + n]);
  } else {
    int j = i - T1;
    int n = j >> 9, c = j & 511;
    woutT[j] = f2bf(w_out[(size_t)c * 512 + n]);
  }
}

// ---------------------------------------------------------------------------
// GroupNorm: x fp32 [32,1024,512] -> z bf16; 32 groups of 16 ch
// ---------------------------------------------------------------------------
__global__ __launch_bounds__(256) void groupnorm_k(
    const float* __restrict__ x, const float* __restrict__ scale,
    const float* __restrict__ bias, u16* __restrict__ z) {
  const int blk = blockIdx.x, b = blk >> 5, g = blk & 31;
  const float* xb = x + (size_t)b * 524288 + g * 16;
  u16* zb = z + (size_t)b * 524288 + g * 16;
  const int tid = threadIdx.x, lane = tid & 63, wid = tid >> 6;

  float4 vv[16];
  float s = 0.f, ss = 0.f;
#pragma unroll
  for (int i = 0; i < 16; ++i) {
    int e = (i * 256 + tid) * 4;
    int hw = e >> 4, j = e & 15;
    vv[i] = *(const float4*)&xb[(size_t)hw * 512 + j];
    s += vv[i].x + vv[i].y + vv[i].z + vv[i].w;
    ss += vv[i].x * vv[i].x + vv[i].y * vv[i].y + vv[i].z * vv[i].z + vv[i].w * vv[i].w;
  }
#pragma unroll
  for (int off = 32; off; off >>= 1) {
    s += __shfl_xor(s, off);
    ss += __shfl_xor(ss, off);
  }
  __shared__ float rs[4], rq[4];
  if (!lane) { rs[wid] = s; rq[wid] = ss; }
  __syncthreads();
  float S_ = rs[0] + rs[1] + rs[2] + rs[3];
  float Q_ = rq[0] + rq[1] + rq[2] + rq[3];
  const float inv_n = 1.f / 16384.f;
  float mean = S_ * inv_n;
  float var = Q_ * inv_n - mean * mean;
  float rstd = rsqrtf(var + 1e-5f);

  int j0 = (tid * 4) & 15;
  float sc0 = scale[g * 16 + j0 + 0] * rstd, sc1 = scale[g * 16 + j0 + 1] * rstd;
  float sc2 = scale[g * 16 + j0 + 2] * rstd, sc3 = scale[g * 16 + j0 + 3] * rstd;
  float bi0 = bias[g * 16 + j0 + 0] - mean * sc0, bi1 = bias[g * 16 + j0 + 1] - mean * sc1;
  float bi2 = bias[g * 16 + j0 + 2] - mean * sc2, bi3 = bias[g * 16 + j0 + 3] - mean * sc3;
#pragma unroll
  for (int i = 0; i < 16; ++i) {
    int e = (i * 256 + tid) * 4;
    int hw = e >> 4, j = e & 15;
    ushort4 o;
    o.x = f2bf(vv[i].x * sc0 + bi0);
    o.y = f2bf(vv[i].y * sc1 + bi1);
    o.z = f2bf(vv[i].z * sc2 + bi2);
    o.w = f2bf(vv[i].w * sc3 + bi3);
    *(ushort4*)&zb[(size_t)hw * 512 + j] = o;
  }
}

// ---------------------------------------------------------------------------
// 8-phase 256x256xBK64 GEMM: C[M,N] = A[M,K] @ Bt[N,K]^T
// 512 thr = 8 waves (2M x 4N), per-wave 128x64 C, acc[8][4].
// Fragment-reuse schedule: per K-tile, bq (B-quarter, 8 b128) loaded once at
// q0 and held; phase q loads af rows {2q,2q+1} (4 b128) -> 24 b128/wave/tile.
// LDS XOR-granule swizzle (pre-swizzled global src, swizzled ds_read).
// Ownership staging: wave pair owns one half-tile, 8 gloads at q0 for tile
// t+1, vmcnt(0) self-drain at q3 (~3.5 phases slack).
// EPI 0: q,k rowmajor (+bias, q scaled), v -> TRANSPOSED [b][c][p]
// EPI 1: bf16 store   EPI 2: fp32 +bias+resid
// ---------------------------------------------------------------------------
#define QSCALE 0.04419417382415922f

template <int EPI>
__global__ __launch_bounds__(512, 2) void gemm8p(
    const u16* __restrict__ A, const u16* __restrict__ Bt,
    int gx, int gxy, int N, int K,
    long long sAb, long long sBb, long long sCb,
    const float* __restrict__ bias, const float* __restrict__ resid,
    u16* __restrict__ qb, u16* __restrict__ kb, u16* __restrict__ vt,
    u16* __restrict__ outb, float* __restrict__ outf) {
  // XCD-chunked bijective remap over the flattened grid (nb % 8 == 0 here)
  int nb = gridDim.x, orig = blockIdx.x, id = orig;
  if (!(nb & 7)) { int chunk = nb >> 3; id = (orig & 7) * chunk + (orig >> 3); }
  int z = id / gxy; int r2 = id - z * gxy;
  int by = r2 / gx; int bx = r2 - by * gx;

  const u16* Ab = A + (size_t)z * sAb;
  const u16* Bb = Bt + (size_t)z * sBb;

  __shared__ u16 As[2][2][8192];  // [buf][half][128*64]
  __shared__ u16 Bs[2][2][8192];

  const int tid = threadIdx.x;
  const int lane = tid & 63, wid = tid >> 6;
  const int wm = wid & 1, wn = wid >> 1;
  const int l15 = lane & 15, l4 = lane >> 4;
  const int m0 = by * 256, n0 = bx * 256;

  // staging ownership: wid 0,1 -> A h0; 2,3 -> A h1; 4,5 -> B h0; 6,7 -> B h1
  const int own_is_b = wid >> 2;
  const int own_h = (wid >> 1) & 1;
  const int prow = ((wid & 1) << 6) | lane;        // 0..127 within pair
  const int srow = prow >> 3;
  const int scol = ((prow & 7) ^ (srow & 7)) << 3; // pre-swizzled src col
  const u16* own_base = (own_is_b ? Bb : Ab) +
      (size_t)((own_is_b ? n0 : m0) + own_h * 128 + srow) * K + scol;
  const int ldsbase = ((wid & 1) << 6) * 8;        // ushort offset, wave-uniform

  f32x4 acc[8][4];
#pragma unroll
  for (int i = 0; i < 8; ++i)
#pragma unroll
    for (int j = 0; j < 4; ++j)
#pragma unroll
      for (int r = 0; r < 4; ++r) acc[i][j][r] = 0.f;

  const int NT = K >> 6;

  auto stage = [&](int k0, int buf) {
    u16* l0 = (own_is_b ? &Bs[buf][own_h][0] : &As[buf][own_h][0]) + ldsbase;
    const u16* g0 = own_base + k0;
#pragma unroll
    for (int j = 0; j < 8; ++j)
      gload16(g0 + (size_t)(j * 16) * K, l0 + j * 1024);
  };

  // prologue: tile 0 into buf 0
  stage(0, 0);
  asm volatile("s_waitcnt vmcnt(0)" ::: "memory");
  __builtin_amdgcn_s_barrier();

  for (int t = 0; t < NT; ++t) {
    const int cur = t & 1;
    const bool pre = (t + 1 < NT);
    const u16* Ah = &As[cur][wm][0];
    const u16* Bh = &Bs[cur][wn >> 1][0];
    const int rbB = (wn & 1) << 6;
    bf16x8 bq[4][2];
#pragma unroll
    for (int q = 0; q < 4; ++q) {
      bf16x8 af[2][2];
      if (q == 0) {
#pragma unroll
        for (int i = 0; i < 4; ++i) {
          const int rr = rbB + i * 16 + l15;
          const int sw = rr & 7;
          bq[i][0] = *(const bf16x8*)&Bh[rr * 64 + ((l4 ^ sw) << 3)];
          bq[i][1] = *(const bf16x8*)&Bh[rr * 64 + (((4 + l4) ^ sw) << 3)];
        }
      }
#pragma unroll
      for (int j = 0; j < 2; ++j) {
        const int rr = (q * 2 + j) * 16 + l15;
        const int sw = rr & 7;
        af[j][0] = *(const bf16x8*)&Ah[rr * 64 + ((l4 ^ sw) << 3)];
        af[j][1] = *(const bf16x8*)&Ah[rr * 64 + (((4 + l4) ^ sw) << 3)];
      }
      if (q == 0 && pre) stage((t + 1) << 6, cur ^ 1);
      __builtin_amdgcn_s_barrier();
      asm volatile("s_waitcnt lgkmcnt(0)" ::: "memory");
      __builtin_amdgcn_sched_barrier(0);
      __builtin_amdgcn_s_setprio(1);
#pragma unroll
      for (int j = 0; j < 2; ++j)
#pragma unroll
        for (int ni = 0; ni < 4; ++ni) {
          acc[q * 2 + j][ni] = __builtin_amdgcn_mfma_f32_16x16x32_bf16(
              af[j][0], bq[ni][0], acc[q * 2 + j][ni], 0, 0, 0);
          acc[q * 2 + j][ni] = __builtin_amdgcn_mfma_f32_16x16x32_bf16(
              af[j][1], bq[ni][1], acc[q * 2 + j][ni], 0, 0, 0);
        }
      __builtin_amdgcn_s_setprio(0);
      if (q == 3 && pre) asm volatile("s_waitcnt vmcnt(0)" ::: "memory");
      __builtin_amdgcn_s_barrier();
    }
  }

  // epilogue
#pragma unroll
  for (int mi = 0; mi < 8; ++mi) {
#pragma unroll
    for (int ni = 0; ni < 4; ++ni) {
      const int gr0 = m0 + wm * 128 + mi * 16 + l4 * 4;
      const int gc = n0 + wn * 64 + ni * 16 + l15;
      if (EPI == 0) {
        const int bsel = gc >> 9, cin = gc & 511;
        const float bs = bias[gc];
        if (bsel < 2) {
          u16* dst = bsel ? kb : qb;
#pragma unroll
          for (int r = 0; r < 4; ++r) {
            float vvv = acc[mi][ni][r] + bs;
            if (bsel == 0) vvv *= QSCALE;
            dst[(size_t)(gr0 + r) * 512 + cin] = f2bf(vvv);
          }
        } else {
          ushort4 o;
          o.x = f2bf(acc[mi][ni][0] + bs);
          o.y = f2bf(acc[mi][ni][1] + bs);
          o.z = f2bf(acc[mi][ni][2] + bs);
          o.w = f2bf(acc[mi][ni][3] + bs);
          const int bb = gr0 >> 10, p = gr0 & 1023;
          *(ushort4*)&vt[(size_t)bb * 524288 + (size_t)cin * 1024 + p] = o;
        }
      } else if (EPI == 1) {
#pragma unroll
        for (int r = 0; r < 4; ++r)
          outb[(size_t)z * sCb + (size_t)(gr0 + r) * N + gc] = f2bf(acc[mi][ni][r]);
      } else {
#pragma unroll
        for (int r = 0; r < 4; ++r)
          outf[(size_t)(gr0 + r) * N + gc] =
              acc[mi][ni][r] + bias[gc] + resid[(size_t)(gr0 + r) * N + gc];
      }
    }
  }
}

// ---------------------------------------------------------------------------
// Row softmax over S bf16 [32768 rows][1024], in place, fp32 math
// ---------------------------------------------------------------------------
__global__ __launch_bounds__(256) void softmax_rows(u16* __restrict__ S) {
  const size_t row = blockIdx.x;
  u16* p = S + row * 1024;
  const int tid = threadIdx.x, lane = tid & 63, wid = tid >> 6;
  ushort4 raw = ((const ushort4*)p)[tid];
  float v0 = bf2f(raw.x), v1 = bf2f(raw.y), v2 = bf2f(raw.z), v3 = bf2f(raw.w);
  float mx = fmaxf(fmaxf(v0, v1), fmaxf(v2, v3));
#pragma unroll
  for (int off = 32; off; off >>= 1) mx = fmaxf(mx, __shfl_xor(mx, off));
  __shared__ float red[8];
  if (!lane) red[wid] = mx;
  __syncthreads();
  mx = fmaxf(fmaxf(red[0], red[1]), fmaxf(red[2], red[3]));
  float e0 = __expf(v0 - mx), e1 = __expf(v1 - mx), e2 = __expf(v2 - mx), e3 = __expf(v3 - mx);
  float s = e0 + e1 + e2 + e3;
#pragma unroll
  for (int off = 32; off; off >>= 1) s += __shfl_xor(s, off);
  if (!lane) red[4 + wid] = s;
  __syncthreads();
  float inv = 1.0f / (red[4] + red[5] + red[6] + red[7]);
  ushort4 o;
  o.x = f2bf(e0 * inv); o.y = f2bf(e1 * inv); o.z = f2bf(e2 * inv); o.w = f2bf(e3 * inv);
  ((ushort4*)p)[tid] = o;
}

// ---------------------------------------------------------------------------
extern "C" void kernel_launch(void* const* d_in, const int* in_sizes, int n_in,
                              void* d_out, int out_size, void* d_ws, size_t ws_size,
                              hipStream_t stream) {
  const float* x = (const float*)d_in[0];
  const float* gn_scale = (const float*)d_in[2];
  const float* gn_bias = (const float*)d_in[3];
  const float* w_qkv = (const float*)d_in[4];
  const float* b_qkv = (const float*)d_in[5];
  const float* w_out = (const float*)d_in[6];
  const float* b_out = (const float*)d_in[7];
  float* out = (float*)d_out;

  char* ws = (char*)d_ws;
  const size_t MB = 1024ull * 1024ull;
  u16* qb = (u16*)(ws + 0 * MB);      // 32 MB  [32768][512]
  u16* kb = (u16*)(ws + 32 * MB);     // 32 MB  [32768][512]
  u16* vt = (u16*)(ws + 64 * MB);     // 32 MB  [32][512][1024]  (V transposed)
  u16* zO = (u16*)(ws + 128 * MB);    // 32 MB  z, later reused as O
  u16* S = (u16*)(ws + 160 * MB);     // 64 MB  [32][1024][1024]
  u16* wqkvT = (u16*)(ws + 224 * MB); // 1.5 MB [1536][512]
  u16* woutT = (u16*)(ws + 226 * MB); // 0.5 MB [512][512]

  prep_weights<<<4096, 256, 0, stream>>>(w_qkv, w_out, wqkvT, woutT);
  groupnorm_k<<<1024, 256, 0, stream>>>(x, gn_scale, gn_bias, zO);

  // QKV: z[32768,512] @ wqkvT^T -> q,k (rowmajor), v (transposed)  grid 6x128
  gemm8p<0><<<768, 512, 0, stream>>>(
      zO, wqkvT, 6, 768, 1536, 512, 0, 0, 0, b_qkv, nullptr,
      qb, kb, vt, nullptr, nullptr);

  // S = q @ k^T (batched over 32; grid 4x4x32 = 512)
  gemm8p<1><<<512, 512, 0, stream>>>(
      qb, kb, 4, 16, 1024, 512, 1024 * 512, 1024 * 512, 1024 * 1024,
      nullptr, nullptr, nullptr, nullptr, nullptr, S, nullptr);

  softmax_rows<<<32768, 256, 0, stream>>>(S);

  // O = P @ V  (vt is [512][1024] per batch; grid 2x4x32 = 256)
  gemm8p<1><<<256, 512, 0, stream>>>(
      S, vt, 2, 8, 512, 1024, 1024 * 1024, 512 * 1024, 1024 * 512,
      nullptr, nullptr, nullptr, nullptr, nullptr, zO, nullptr);

  // out = O @ w_out^T + b_out + x  (grid 2x128 = 256)
  gemm8p<2><<<256, 512, 0, stream>>>(
      zO, woutT, 2, 256, 512, 512, 0, 0, 0, b_out, x,
      nullptr, nullptr, nullptr, nullptr, out);
}